// Round 7
// baseline (305.211 us; speedup 1.0000x reference)
//
#include <hip/hip_runtime.h>

// SSIM loss, fused separable, streaming ring-buffer kernel (round 7).
// B*C=48 images of 512x512 fp32, 11x11 Gaussian window, separable via
// row-sums (w1[i] = sum_j window[i][j]; sum(w1)==1).
//
// vs round 6 (163 us, VALU 29%, latency-bound):
//  - 4 fields not 5: SSIM needs blur(p), blur(t), blur(p^2+t^2), blur(p*t)
//    only (v1+v2 = blur(p^2+t^2) - m1^2 - m2^2 by linearity). -20% conv/LDS.
//  - 64-row ring buffer (&63) replaces the 10-row halo copy: 2 barriers/iter.
//  - 1536 blocks (48 img x 16 bands x 2 row-halves, 9 iters of 32 rows each,
//    10-row overlap recompute) + __launch_bounds__(256,4): 4 blocks/CU
//    resident, 6 slots/CU -> stall filling that round 6's 3 blocks lacked.
// SROA rules (rounds 2-4): no local array passed to functions; float4
// components extracted BY NAME; constant indices only.
// Tail rules (round 4-5): fire-and-forget f64 atomics into 128 slots,
// separate 1-wave finalize kernel; NO fence/returning-atomic tail.

#define WSZ   11
#define RAD   5
#define BAND  32
#define RING  64
#define BLOCK 256
#define NWAVE (BLOCK/64)
#define NSLOT 128
#define NITER 9
#define HALF  256

// Horizontal 11-tap conv of src[0..13] -> 4 outputs -> one b128 LDS store.
#define HCONV_STORE(src, f)                                              \
    {                                                                    \
        float s0 = 0.f, s1 = 0.f, s2 = 0.f, s3 = 0.f;                    \
        _Pragma("unroll")                                                \
        for (int k = 0; k < WSZ; ++k) {                                  \
            const float wk = w[k];                                       \
            s0 += wk * src[k];                                           \
            s1 += wk * src[k + 1];                                       \
            s2 += wk * src[k + 2];                                       \
            s3 += wk * src[k + 3];                                       \
        }                                                                \
        *reinterpret_cast<float4*>(&buf[f][slot][4 * hg]) =              \
            make_float4(s0, s1, s2, s3);                                 \
    }

// Vertical 11-tap conv of field f over ring rows (Lr0..Lr0+17)&63 -> res[8].
#define VCONV(f, res)                                                    \
    {                                                                    \
        float col[18];                                                   \
        _Pragma("unroll")                                                \
        for (int k = 0; k < 18; ++k)                                     \
            col[k] = buf[f][(Lr0 + k + RING) & (RING - 1)][c];           \
        _Pragma("unroll")                                                \
        for (int j = 0; j < 8; ++j) {                                    \
            float s = 0.f;                                               \
            _Pragma("unroll")                                            \
            for (int k = 0; k < WSZ; ++k) s += w[k] * col[j + k];        \
            res[j] = s;                                                  \
        }                                                                \
    }

__global__ __launch_bounds__(BLOCK, 4) void ssim_ring_kernel(
    const float* __restrict__ pred,
    const float* __restrict__ target,
    const float* __restrict__ window,
    double* __restrict__ acc,          // NSLOT slots
    int H, int W)
{
    __shared__ float buf[4][RING][BAND];   // 32 KB: mu1s, mu2s, p^2+t^2, p*t
    __shared__ float w1s[WSZ];
    __shared__ float wavesum[NWAVE];

    const int t = threadIdx.x;

    // Recover separable 1D window (row sums of the 2D window).
    if (t < WSZ) {
        float s = 0.f;
        #pragma unroll
        for (int j = 0; j < WSZ; ++j) s += window[t * WSZ + j];
        w1s[t] = s;
    }

    // Zero the ring (v-pass of early iters reads guarded-out slots).
    {
        float4* bz = reinterpret_cast<float4*>(&buf[0][0][0]);
        const float4 z = make_float4(0.f, 0.f, 0.f, 0.f);
        for (int l = t; l < 4 * RING * BAND / 4; l += BLOCK) bz[l] = z;
    }

    // Block decode: 48 img x 16 bands x 2 halves = 1536.
    const int half = blockIdx.x & 1;
    const int band = (blockIdx.x >> 1) & 15;
    const int img  = blockIdx.x >> 5;

    const int R0   = half * HALF - 16;     // image row of local L=0
    const int col0 = band * BAND - RAD;

    const float* __restrict__ p = pred   + (size_t)img * H * W;
    const float* __restrict__ q = target + (size_t)img * H * W;

    __syncthreads();
    float w[WSZ];
    #pragma unroll
    for (int k = 0; k < WSZ; ++k) w[k] = w1s[k];

    const bool interior = (band > 0) && (band < 15);
    const int hr = t >> 3, hg = t & 7;     // h-pass: (row 0..31, col-group 0..7)
    const int c  = t & 31,  vg = t >> 5;   // v-pass: (col, 8-row group), vg<4

    float local = 0.f;

    for (int i = 0; i < NITER; ++i) {
        // ---- horizontal pass: input rows R0+32i .. R0+32i+31 -> ring ----
        {
            const int L   = 32 * i + hr;
            const int row = R0 + L;
            const int slot = L & (RING - 1);
            const bool rok = (unsigned)row < (unsigned)H;

            float pv[14], tv[14];          // cols col0+4hg .. col0+4hg+13
            if (interior && rok) {
                const float4* __restrict__ prow =
                    reinterpret_cast<const float4*>(p + (size_t)row * W);
                const float4* __restrict__ qrow =
                    reinterpret_cast<const float4*>(q + (size_t)row * W);
                const int b = band * 8 + hg - 2;   // (band*32+4hg-8)/4, aligned
                const float4 P0 = prow[b],     P1 = prow[b + 1], P2 = prow[b + 2],
                             P3 = prow[b + 3], P4 = prow[b + 4];
                const float4 Q0 = qrow[b],     Q1 = qrow[b + 1], Q2 = qrow[b + 2],
                             Q3 = qrow[b + 3], Q4 = qrow[b + 4];
                pv[0]  = P0.w;
                pv[1]  = P1.x; pv[2]  = P1.y; pv[3]  = P1.z; pv[4]  = P1.w;
                pv[5]  = P2.x; pv[6]  = P2.y; pv[7]  = P2.z; pv[8]  = P2.w;
                pv[9]  = P3.x; pv[10] = P3.y; pv[11] = P3.z; pv[12] = P3.w;
                pv[13] = P4.x;
                tv[0]  = Q0.w;
                tv[1]  = Q1.x; tv[2]  = Q1.y; tv[3]  = Q1.z; tv[4]  = Q1.w;
                tv[5]  = Q2.x; tv[6]  = Q2.y; tv[7]  = Q2.z; tv[8]  = Q2.w;
                tv[9]  = Q3.x; tv[10] = Q3.y; tv[11] = Q3.z; tv[12] = Q3.w;
                tv[13] = Q4.x;
            } else {
                const int cb = col0 + 4 * hg;
                #pragma unroll
                for (int ii = 0; ii < 14; ++ii) {
                    const int gc = cb + ii;
                    const bool ok = rok && ((unsigned)gc < (unsigned)W);
                    const size_t idx = (size_t)row * W + gc;
                    pv[ii] = ok ? p[idx] : 0.f;
                    tv[ii] = ok ? q[idx] : 0.f;
                }
            }

            HCONV_STORE(pv, 0)                    // blur(p) source
            HCONV_STORE(tv, 1)                    // blur(t) source

            float prod[14];
            #pragma unroll
            for (int ii = 0; ii < 14; ++ii) prod[ii] = pv[ii] * pv[ii] + tv[ii] * tv[ii];
            HCONV_STORE(prod, 2)                  // p^2 + t^2
            #pragma unroll
            for (int ii = 0; ii < 14; ++ii) prod[ii] = pv[ii] * tv[ii];
            HCONV_STORE(prod, 3)                  // p*t
        }
        __syncthreads();

        // ---- vertical pass: out local rows 32i-5+8vg .. +7 (vg<4) ----
        if (t < 128) {
            const int Lo0 = 32 * i - 5 + 8 * vg;  // local row of output j=0
            const int Lr0 = Lo0 - 5;              // first ring row read

            float a1[8], a2[8], ass[8], a12[8];
            VCONV(0, a1)
            VCONV(1, a2)
            VCONV(2, ass)
            VCONV(3, a12)

            const float C1  = 1e-4f;   // (0.01*1)^2
            const float C2  = 9e-4f;   // (0.03*1)^2
            const float EPS = 1e-8f;
            const int ro0 = R0 + Lo0;             // image row of output j=0
            #pragma unroll
            for (int j = 0; j < 8; ++j) {
                // valid iff this half owns the row (each row owned once).
                if ((unsigned)(ro0 + j - half * HALF) < (unsigned)HALF) {
                    const float m1 = a1[j], m2 = a2[j];
                    const float m1sq = m1 * m1, m2sq = m2 * m2, m12 = m1 * m2;
                    const float vs = ass[j] - m1sq - m2sq;   // v1 + v2
                    const float cv = a12[j] - m12;           // sigma12
                    const float num = (2.f * m12 + C1) * (2.f * cv + C2);
                    const float den = (m1sq + m2sq + C1) * (vs + C2) + EPS;
                    local += num / den;
                }
            }
        }
        __syncthreads();   // WAR: next h-pass overwrites slots just read
    }

    // Wave shuffle reduce, cross-wave via LDS, one fire-and-forget f64
    // atomic per block into one of 128 slots.
    #pragma unroll
    for (int off = 32; off > 0; off >>= 1)
        local += __shfl_down(local, off, 64);
    const int lane = t & 63, wid = t >> 6;
    if (lane == 0) wavesum[wid] = local;
    __syncthreads();
    if (t == 0) {
        float s = 0.f;
        #pragma unroll
        for (int wv = 0; wv < NWAVE; ++wv) s += wavesum[wv];
        atomicAdd(&acc[blockIdx.x & (NSLOT - 1)], (double)s);
    }
}

__global__ void ssim_finalize_kernel(const double* __restrict__ acc,
                                     float* __restrict__ out, double invN)
{
    const int l = threadIdx.x;
    double s = acc[l] + acc[l + 64];
    #pragma unroll
    for (int off = 32; off > 0; off >>= 1)
        s += __shfl_down(s, off, 64);
    if (l == 0) out[0] = (float)(1.0 - s * invN);
}

extern "C" void kernel_launch(void* const* d_in, const int* in_sizes, int n_in,
                              void* d_out, int out_size, void* d_ws, size_t ws_size,
                              hipStream_t stream)
{
    const float* pred   = (const float*)d_in[0];
    const float* target = (const float*)d_in[1];
    const float* window = (const float*)d_in[2];
    float*  out = (float*)d_out;
    double* acc = (double*)d_ws;

    const int B = 16, C = 3, H = 512, W = 512;
    const int n_img = B * C;
    const int blocks = n_img * (W / BAND) * 2;    // 48 * 16 * 2 = 1536

    // ws is re-poisoned 0xAA before every timed launch: zero the slots.
    hipMemsetAsync(d_ws, 0, NSLOT * sizeof(double), stream);

    ssim_ring_kernel<<<blocks, BLOCK, 0, stream>>>(
        pred, target, window, acc, H, W);

    const double invN = 1.0 / ((double)n_img * H * W);
    ssim_finalize_kernel<<<1, 64, 0, stream>>>(acc, out, invN);
}

// Round 8
// 221.943 us; speedup vs baseline: 1.3752x; 1.3752x over previous
//
#include <hip/hip_runtime.h>

// SSIM loss, fused separable, streaming ring buffer + register prefetch.
// B*C=48 images of 512x512 fp32, 11x11 Gaussian window, separable via
// row-sums (w1[i] = sum_j window[i][j]; sum(w1)==1).
//
// Round-8 vs round-7 (216 us, spill regression):
//  - NO __launch_bounds__ min-waves clause: (256,4) capped RA at 128 VGPR
//    and re-spilled to scratch (WRITE_SIZE 115 MB). Plain (256) only.
//  - Register prefetch pipeline: iteration i's input rows are loaded into
//    pv/tv registers during iteration i-1, so global-load latency overlaps
//    barrier + v-pass + barrier instead of the per-iter critical path
//    (rounds 5-7 all showed every pipe <50% busy = latency-bound).
// Keeps round 7's wins: 4 fields (blur(p), blur(t), blur(p^2+t^2),
// blur(p*t); v1+v2 = blur(p^2+t^2)-m1^2-m2^2), 64-row ring (no halo copy),
// 1536 blocks (48 img x 16 bands x 2 halves, 9 iters x 32 rows).
// SROA rules (rounds 2-4): no local array passed to functions; float4
// components extracted BY NAME; constant indices only; macros for reuse.
// Tail rules (rounds 4-5): fire-and-forget f64 atomics into 128 slots +
// separate 1-wave finalize; NO fence / returning atomic.

#define WSZ   11
#define RAD   5
#define BAND  32
#define RING  64
#define BLOCK 256
#define NWAVE (BLOCK/64)
#define NSLOT 128
#define NITER 9
#define HALF  256

// Fill pv[0..13], tv[0..13] with input row (R0 + 32*iidx + hr), cols
// col0+4*hg .. col0+4*hg+13. Interior: two aligned float4 runs. Border/OOB:
// guarded scalars (zeros outside image = SAME zero padding).
#define LOADROWS(iidx)                                                    \
    {                                                                     \
        const int Lr  = 32 * (iidx) + hr;                                 \
        const int row = R0 + Lr;                                          \
        const bool rok = (unsigned)row < (unsigned)H;                     \
        if (interior && rok) {                                            \
            const float4* __restrict__ prow =                             \
                reinterpret_cast<const float4*>(p + (size_t)row * W);     \
            const float4* __restrict__ qrow =                             \
                reinterpret_cast<const float4*>(q + (size_t)row * W);     \
            const int b = band * 8 + hg - 2;                              \
            const float4 P0 = prow[b],     P1 = prow[b + 1];              \
            const float4 P2 = prow[b + 2], P3 = prow[b + 3];              \
            const float4 P4 = prow[b + 4];                                \
            const float4 Q0 = qrow[b],     Q1 = qrow[b + 1];              \
            const float4 Q2 = qrow[b + 2], Q3 = qrow[b + 3];              \
            const float4 Q4 = qrow[b + 4];                                \
            pv[0]  = P0.w;                                                \
            pv[1]  = P1.x; pv[2]  = P1.y; pv[3]  = P1.z; pv[4]  = P1.w;   \
            pv[5]  = P2.x; pv[6]  = P2.y; pv[7]  = P2.z; pv[8]  = P2.w;   \
            pv[9]  = P3.x; pv[10] = P3.y; pv[11] = P3.z; pv[12] = P3.w;   \
            pv[13] = P4.x;                                                \
            tv[0]  = Q0.w;                                                \
            tv[1]  = Q1.x; tv[2]  = Q1.y; tv[3]  = Q1.z; tv[4]  = Q1.w;   \
            tv[5]  = Q2.x; tv[6]  = Q2.y; tv[7]  = Q2.z; tv[8]  = Q2.w;   \
            tv[9]  = Q3.x; tv[10] = Q3.y; tv[11] = Q3.z; tv[12] = Q3.w;   \
            tv[13] = Q4.x;                                                \
        } else {                                                          \
            const int cb = col0 + 4 * hg;                                 \
            _Pragma("unroll")                                             \
            for (int ii = 0; ii < 14; ++ii) {                             \
                const int gc = cb + ii;                                   \
                const bool ok = rok && ((unsigned)gc < (unsigned)W);      \
                const size_t idx = (size_t)row * W + gc;                  \
                pv[ii] = ok ? p[idx] : 0.f;                               \
                tv[ii] = ok ? q[idx] : 0.f;                               \
            }                                                             \
        }                                                                 \
    }

// Horizontal 11-tap conv of src[0..13] -> 4 outputs -> one b128 LDS store.
#define HCONV_STORE(src, f)                                              \
    {                                                                    \
        float s0 = 0.f, s1 = 0.f, s2 = 0.f, s3 = 0.f;                    \
        _Pragma("unroll")                                                \
        for (int k = 0; k < WSZ; ++k) {                                  \
            const float wk = w[k];                                       \
            s0 += wk * src[k];                                           \
            s1 += wk * src[k + 1];                                       \
            s2 += wk * src[k + 2];                                       \
            s3 += wk * src[k + 3];                                       \
        }                                                                \
        *reinterpret_cast<float4*>(&buf[f][slot][4 * hg]) =              \
            make_float4(s0, s1, s2, s3);                                 \
    }

// Vertical 11-tap conv of field f over ring rows (Lr0..Lr0+17)&63 -> res[8].
#define VCONV(f, res)                                                    \
    {                                                                    \
        float col[18];                                                   \
        _Pragma("unroll")                                                \
        for (int k = 0; k < 18; ++k)                                     \
            col[k] = buf[f][(Lr0 + k + RING) & (RING - 1)][c];           \
        _Pragma("unroll")                                                \
        for (int j = 0; j < 8; ++j) {                                    \
            float s = 0.f;                                               \
            _Pragma("unroll")                                            \
            for (int k = 0; k < WSZ; ++k) s += w[k] * col[j + k];        \
            res[j] = s;                                                  \
        }                                                                \
    }

__global__ __launch_bounds__(BLOCK) void ssim_ring_kernel(
    const float* __restrict__ pred,
    const float* __restrict__ target,
    const float* __restrict__ window,
    double* __restrict__ acc,          // NSLOT slots
    int H, int W)
{
    __shared__ float buf[4][RING][BAND];   // 32 KB: mu1s, mu2s, p^2+t^2, p*t
    __shared__ float w1s[WSZ];
    __shared__ float wavesum[NWAVE];

    const int t = threadIdx.x;

    // Recover separable 1D window (row sums of the 2D window).
    if (t < WSZ) {
        float s = 0.f;
        #pragma unroll
        for (int j = 0; j < WSZ; ++j) s += window[t * WSZ + j];
        w1s[t] = s;
    }

    // Zero the ring (early v-pass iterations read never-written slots).
    {
        float4* bz = reinterpret_cast<float4*>(&buf[0][0][0]);
        const float4 z = make_float4(0.f, 0.f, 0.f, 0.f);
        for (int l = t; l < 4 * RING * BAND / 4; l += BLOCK) bz[l] = z;
    }

    // Block decode: 48 img x 16 bands x 2 halves = 1536.
    const int half = blockIdx.x & 1;
    const int band = (blockIdx.x >> 1) & 15;
    const int img  = blockIdx.x >> 5;

    const int R0   = half * HALF - 16;     // image row of local L=0
    const int col0 = band * BAND - RAD;

    const float* __restrict__ p = pred   + (size_t)img * H * W;
    const float* __restrict__ q = target + (size_t)img * H * W;

    __syncthreads();
    float w[WSZ];
    #pragma unroll
    for (int k = 0; k < WSZ; ++k) w[k] = w1s[k];

    const bool interior = (band > 0) && (band < 15);
    const int hr = t >> 3, hg = t & 7;     // h-pass: (row 0..31, col-group 0..7)
    const int c  = t & 31,  vg = t >> 5;   // v-pass: (col, 8-row group), vg<4

    float local = 0.f;
    float pv[14], tv[14];

    LOADROWS(0)                            // prologue: iter-0 rows in flight

    for (int i = 0; i < NITER; ++i) {
        // ---- horizontal pass from prefetched registers -> ring ----
        {
            const int slot = (32 * i + hr) & (RING - 1);

            HCONV_STORE(pv, 0)                    // blur(p) source
            HCONV_STORE(tv, 1)                    // blur(t) source

            float prod[14];
            #pragma unroll
            for (int ii = 0; ii < 14; ++ii) prod[ii] = pv[ii] * pv[ii] + tv[ii] * tv[ii];
            HCONV_STORE(prod, 2)                  // p^2 + t^2
            #pragma unroll
            for (int ii = 0; ii < 14; ++ii) prod[ii] = pv[ii] * tv[ii];
            HCONV_STORE(prod, 3)                  // p*t
        }

        // ---- prefetch iter i+1 rows; latency overlaps barrier+v-pass ----
        LOADROWS(i + 1)                    // i+1 == NITER rows are OOB -> zeros

        __syncthreads();

        // ---- vertical pass: out local rows 32i-5+8vg .. +7 (vg<4) ----
        if (t < 128) {
            const int Lo0 = 32 * i - 5 + 8 * vg;  // local row of output j=0
            const int Lr0 = Lo0 - 5;              // first ring row read

            float a1[8], a2[8], ass[8], a12[8];
            VCONV(0, a1)
            VCONV(1, a2)
            VCONV(2, ass)
            VCONV(3, a12)

            const float C1  = 1e-4f;   // (0.01*1)^2
            const float C2  = 9e-4f;   // (0.03*1)^2
            const float EPS = 1e-8f;
            const int ro0 = R0 + Lo0;             // image row of output j=0
            #pragma unroll
            for (int j = 0; j < 8; ++j) {
                // valid iff this half owns the row (each row owned once).
                if ((unsigned)(ro0 + j - half * HALF) < (unsigned)HALF) {
                    const float m1 = a1[j], m2 = a2[j];
                    const float m1sq = m1 * m1, m2sq = m2 * m2, m12 = m1 * m2;
                    const float vs = ass[j] - m1sq - m2sq;   // v1 + v2
                    const float cv = a12[j] - m12;           // sigma12
                    const float num = (2.f * m12 + C1) * (2.f * cv + C2);
                    const float den = (m1sq + m2sq + C1) * (vs + C2) + EPS;
                    local += num / den;
                }
            }
        }
        __syncthreads();   // WAR: next h-pass overwrites slots just read
    }

    // Wave shuffle reduce, cross-wave via LDS, one fire-and-forget f64
    // atomic per block into one of 128 slots.
    #pragma unroll
    for (int off = 32; off > 0; off >>= 1)
        local += __shfl_down(local, off, 64);
    const int lane = t & 63, wid = t >> 6;
    if (lane == 0) wavesum[wid] = local;
    __syncthreads();
    if (t == 0) {
        float s = 0.f;
        #pragma unroll
        for (int wv = 0; wv < NWAVE; ++wv) s += wavesum[wv];
        atomicAdd(&acc[blockIdx.x & (NSLOT - 1)], (double)s);
    }
}

__global__ void ssim_finalize_kernel(const double* __restrict__ acc,
                                     float* __restrict__ out, double invN)
{
    const int l = threadIdx.x;
    double s = acc[l] + acc[l + 64];
    #pragma unroll
    for (int off = 32; off > 0; off >>= 1)
        s += __shfl_down(s, off, 64);
    if (l == 0) out[0] = (float)(1.0 - s * invN);
}

extern "C" void kernel_launch(void* const* d_in, const int* in_sizes, int n_in,
                              void* d_out, int out_size, void* d_ws, size_t ws_size,
                              hipStream_t stream)
{
    const float* pred   = (const float*)d_in[0];
    const float* target = (const float*)d_in[1];
    const float* window = (const float*)d_in[2];
    float*  out = (float*)d_out;
    double* acc = (double*)d_ws;

    const int B = 16, C = 3, H = 512, W = 512;
    const int n_img = B * C;
    const int blocks = n_img * (W / BAND) * 2;    // 48 * 16 * 2 = 1536

    // ws is re-poisoned 0xAA before every timed launch: zero the slots.
    hipMemsetAsync(d_ws, 0, NSLOT * sizeof(double), stream);

    ssim_ring_kernel<<<blocks, BLOCK, 0, stream>>>(
        pred, target, window, acc, H, W);

    const double invN = 1.0 / ((double)n_img * H * W);
    ssim_finalize_kernel<<<1, 64, 0, stream>>>(acc, out, invN);
}

// Round 9
// 199.782 us; speedup vs baseline: 1.5277x; 1.1109x over previous
//
#include <hip/hip_runtime.h>

// SSIM loss, fused separable, BARRIER-FREE single-wave streaming kernel.
// B*C=48 images of 512x512 fp32, 11x11 Gaussian window, separable via
// row-sums (w1[i] = sum_j window[i][j]; sum(w1)==1).
//
// Round-9 theory: rounds 5/6/8 all plateau at ~1 TB/s effective fetch with
// every pipe <35% busy. Cause: the compiler emits s_waitcnt vmcnt(0) before
// EVERY s_barrier (syncthreads semantics), so register prefetch is drained
// at each barrier -> ~900-cyc HBM latency on every iteration's critical
// path, synchronized across the block's waves. Fix: single-wave blocks.
// A wave's DS ops execute in order, so producer->consumer through LDS
// within one wave needs NO barrier; with zero barriers there is no drain
// point and prefetched loads stay in flight across iterations.
//  - 3072 blocks x 64 threads: 48 img x 16 col-bands(32) x 4 row-strips(128).
//  - Ring: 32 rows x 32 cols x float4 (mu1s,mu2s,p^2+t^2,pt packed) = 16 KB
//    -> ~9 resident single-wave blocks/CU, independent (no common stalls).
//  - 19 iters: h-blur 8 rows (from regs prefetched LAST iter), 4 b128 ring
//    writes/lane; v-conv 8 out rows (2 groups x 4), 14 b128 ring reads/lane
//    (all 4 fields per read); SSIM; ownership-guarded accumulate.
//  - Prefetch split: loads issue into P0..P4/Q0..Q4 at iter end, extraction
//    happens at next iter top -> vmcnt wait lands ~1500 cyc after issue.
// SROA rules (rounds 2-4): no local array passed to functions; float4
// components BY NAME; constant indices only. Tail rules (rounds 4-5):
// per-block slot WRITE (no atomic, no memset) + tiny finalize kernel.

#define WSZ   11
#define RAD   5
#define IMGN  48
#define IMGH  512
#define IMGW  512
#define BAND  32
#define RINGN 32
#define OWNR  128          // output rows owned per block
#define NITER 19
#define NBLK  (IMGN * 16 * 4)   // 3072

// Issue next iteration's global loads into P0..P4 / Q0..Q4 (float4 regs).
// Interior+row-ok: 10 aligned dwordx4 loads. Otherwise: guarded scalars
// written into the SAME component slots the extractor reads (others = 0).
#define PREFETCH(ii)                                                      \
    {                                                                     \
        const int row = R0 + 8 * (ii) + hrr;                              \
        const bool rok = (unsigned)row < (unsigned)IMGH;                  \
        if (interior && rok) {                                            \
            const float4* __restrict__ prow =                             \
                reinterpret_cast<const float4*>(p + row * IMGW);          \
            const float4* __restrict__ qrow =                             \
                reinterpret_cast<const float4*>(q + row * IMGW);          \
            P0 = prow[b]; P1 = prow[b + 1]; P2 = prow[b + 2];             \
            P3 = prow[b + 3]; P4 = prow[b + 4];                           \
            Q0 = qrow[b]; Q1 = qrow[b + 1]; Q2 = qrow[b + 2];             \
            Q3 = qrow[b + 3]; Q4 = qrow[b + 4];                           \
        } else {                                                          \
            const int cb = col0 + 4 * hg;                                 \
            const int base = row * IMGW;                                  \
            P0 = make_float4(0.f, 0.f, 0.f, 0.f);                         \
            P4 = P3 = P2 = P1 = P0;                                       \
            Q4 = Q3 = Q2 = Q1 = Q0 = P0;                                  \
            if (rok) {                                                    \
                const bool o0 = (unsigned)(cb)      < (unsigned)IMGW;     \
                const bool o1 = (unsigned)(cb + 1)  < (unsigned)IMGW;     \
                const bool o2 = (unsigned)(cb + 2)  < (unsigned)IMGW;     \
                const bool o3 = (unsigned)(cb + 3)  < (unsigned)IMGW;     \
                const bool o4 = (unsigned)(cb + 4)  < (unsigned)IMGW;     \
                const bool o5 = (unsigned)(cb + 5)  < (unsigned)IMGW;     \
                const bool o6 = (unsigned)(cb + 6)  < (unsigned)IMGW;     \
                const bool o7 = (unsigned)(cb + 7)  < (unsigned)IMGW;     \
                const bool o8 = (unsigned)(cb + 8)  < (unsigned)IMGW;     \
                const bool o9 = (unsigned)(cb + 9)  < (unsigned)IMGW;     \
                const bool oa = (unsigned)(cb + 10) < (unsigned)IMGW;     \
                const bool ob = (unsigned)(cb + 11) < (unsigned)IMGW;     \
                const bool oc = (unsigned)(cb + 12) < (unsigned)IMGW;     \
                const bool od = (unsigned)(cb + 13) < (unsigned)IMGW;     \
                P0.w = o0 ? p[base + cb]      : 0.f;                      \
                P1.x = o1 ? p[base + cb + 1]  : 0.f;                      \
                P1.y = o2 ? p[base + cb + 2]  : 0.f;                      \
                P1.z = o3 ? p[base + cb + 3]  : 0.f;                      \
                P1.w = o4 ? p[base + cb + 4]  : 0.f;                      \
                P2.x = o5 ? p[base + cb + 5]  : 0.f;                      \
                P2.y = o6 ? p[base + cb + 6]  : 0.f;                      \
                P2.z = o7 ? p[base + cb + 7]  : 0.f;                      \
                P2.w = o8 ? p[base + cb + 8]  : 0.f;                      \
                P3.x = o9 ? p[base + cb + 9]  : 0.f;                      \
                P3.y = oa ? p[base + cb + 10] : 0.f;                      \
                P3.z = ob ? p[base + cb + 11] : 0.f;                      \
                P3.w = oc ? p[base + cb + 12] : 0.f;                      \
                P4.x = od ? p[base + cb + 13] : 0.f;                      \
                Q0.w = o0 ? q[base + cb]      : 0.f;                      \
                Q1.x = o1 ? q[base + cb + 1]  : 0.f;                      \
                Q1.y = o2 ? q[base + cb + 2]  : 0.f;                      \
                Q1.z = o3 ? q[base + cb + 3]  : 0.f;                      \
                Q1.w = o4 ? q[base + cb + 4]  : 0.f;                      \
                Q2.x = o5 ? q[base + cb + 5]  : 0.f;                      \
                Q2.y = o6 ? q[base + cb + 6]  : 0.f;                      \
                Q2.z = o7 ? q[base + cb + 7]  : 0.f;                      \
                Q2.w = o8 ? q[base + cb + 8]  : 0.f;                      \
                Q3.x = o9 ? q[base + cb + 9]  : 0.f;                      \
                Q3.y = oa ? q[base + cb + 10] : 0.f;                      \
                Q3.z = ob ? q[base + cb + 11] : 0.f;                      \
                Q3.w = oc ? q[base + cb + 12] : 0.f;                      \
                Q4.x = od ? q[base + cb + 13] : 0.f;                      \
            }                                                             \
        }                                                                 \
    }

__global__ __launch_bounds__(64) void ssim_wave_kernel(
    const float* __restrict__ pred,
    const float* __restrict__ target,
    const float* __restrict__ window,
    double* __restrict__ slots)        // NBLK slots, plain write per block
{
    __shared__ float4 buf[RINGN][BAND];   // 16 KB ring: (mu1s,mu2s,ss,pt)

    const int t = threadIdx.x;

    // Recover separable 1D window via row sums; broadcast with shuffles
    // (no LDS, no barrier).
    float rsum = 0.f;
    if (t < WSZ) {
        #pragma unroll
        for (int j = 0; j < WSZ; ++j) rsum += window[t * WSZ + j];
    }
    float w[WSZ];
    #pragma unroll
    for (int k = 0; k < WSZ; ++k) w[k] = __shfl(rsum, k, 64);

    // Block decode: 48 img x 16 bands x 4 strips.
    const int strip = blockIdx.x & 3;
    const int band  = (blockIdx.x >> 2) & 15;
    const int img   = blockIdx.x >> 6;

    const int own0 = strip * OWNR;
    const int R0   = own0 - 16;            // image row of local L=0
    const int col0 = band * BAND - RAD;

    const float* __restrict__ p = pred   + (size_t)img * IMGH * IMGW;
    const float* __restrict__ q = target + (size_t)img * IMGH * IMGW;

    const bool interior = (band > 0) && (band < 15);
    const int hrr = t >> 3, hg = t & 7;    // h-pass: (row 0..7, col-group 0..7)
    const int c   = t & 31, vg = t >> 5;   // v-pass: (col, 4-row group 0..1)
    const int b   = band * 8 + hg - 2;     // aligned float4 index (interior)

    float4 P0, P1, P2, P3, P4, Q0, Q1, Q2, Q3, Q4;
    float local = 0.f;

    PREFETCH(0)

    #pragma unroll 1
    for (int i = 0; i < NITER; ++i) {
        // ---- extract prefetched rows (vmcnt wait lands here) ----
        float pv[14], tv[14];
        pv[0]  = P0.w;
        pv[1]  = P1.x; pv[2]  = P1.y; pv[3]  = P1.z; pv[4]  = P1.w;
        pv[5]  = P2.x; pv[6]  = P2.y; pv[7]  = P2.z; pv[8]  = P2.w;
        pv[9]  = P3.x; pv[10] = P3.y; pv[11] = P3.z; pv[12] = P3.w;
        pv[13] = P4.x;
        tv[0]  = Q0.w;
        tv[1]  = Q1.x; tv[2]  = Q1.y; tv[3]  = Q1.z; tv[4]  = Q1.w;
        tv[5]  = Q2.x; tv[6]  = Q2.y; tv[7]  = Q2.z; tv[8]  = Q2.w;
        tv[9]  = Q3.x; tv[10] = Q3.y; tv[11] = Q3.z; tv[12] = Q3.w;
        tv[13] = Q4.x;

        // ---- issue next iteration's loads (stay in flight, no barrier) ----
        if (i + 1 < NITER) PREFETCH(i + 1)

        // ---- horizontal pass: 8 rows -> ring (4 b128 writes / lane) ----
        {
            const int slot = (8 * i + hrr) & (RINGN - 1);
            float ss[14], pt[14];
            #pragma unroll
            for (int ii = 0; ii < 14; ++ii) {
                ss[ii] = pv[ii] * pv[ii] + tv[ii] * tv[ii];
                pt[ii] = pv[ii] * tv[ii];
            }
            #pragma unroll
            for (int j = 0; j < 4; ++j) {
                float f0 = 0.f, f1 = 0.f, f2 = 0.f, f3 = 0.f;
                #pragma unroll
                for (int k = 0; k < WSZ; ++k) {
                    const float wk = w[k];
                    f0 += wk * pv[j + k];
                    f1 += wk * tv[j + k];
                    f2 += wk * ss[j + k];
                    f3 += wk * pt[j + k];
                }
                buf[slot][4 * hg + j] = make_float4(f0, f1, f2, f3);
            }
        }
        __builtin_amdgcn_wave_barrier();   // compiler fence only (no HW sync)

        // ---- vertical pass: 8 out rows (2 groups x 4); i>=2 only ----
        if (i >= 2) {
            const int Lo0 = 8 * i - 5 + 4 * vg;   // local out row of j=0
            const int Lr0 = Lo0 - 5;              // first ring row read (>=6)

            float acc[4][4];
            #pragma unroll
            for (int f = 0; f < 4; ++f)
                #pragma unroll
                for (int j = 0; j < 4; ++j) acc[f][j] = 0.f;

            #pragma unroll
            for (int k = 0; k < 14; ++k) {
                const int rr = (Lr0 + k) & (RINGN - 1);
                const float4 v = buf[rr][c];
                #pragma unroll
                for (int j = 0; j < 4; ++j) {
                    const int kk = k - j;
                    if (kk >= 0 && kk < WSZ) {
                        const float wk = w[kk];
                        acc[0][j] += wk * v.x;
                        acc[1][j] += wk * v.y;
                        acc[2][j] += wk * v.z;
                        acc[3][j] += wk * v.w;
                    }
                }
            }

            const float C1  = 1e-4f;   // (0.01*1)^2
            const float C2  = 9e-4f;   // (0.03*1)^2
            const float EPS = 1e-8f;
            #pragma unroll
            for (int j = 0; j < 4; ++j) {
                const int rel = Lo0 + j - 16;     // row index within owned 128
                if ((unsigned)rel < (unsigned)OWNR) {
                    const float m1 = acc[0][j], m2 = acc[1][j];
                    const float m1sq = m1 * m1, m2sq = m2 * m2, m12 = m1 * m2;
                    const float vs = acc[2][j] - m1sq - m2sq;  // v1 + v2
                    const float cv = acc[3][j] - m12;          // sigma12
                    const float num = (2.f * m12 + C1) * (2.f * cv + C2);
                    const float den = (m1sq + m2sq + C1) * (vs + C2) + EPS;
                    local += num / den;
                }
            }
        }
        __builtin_amdgcn_wave_barrier();   // fence before next h overwrite
    }

    // Wave shuffle reduce; lane 0 writes this block's slot (no atomic).
    #pragma unroll
    for (int off = 32; off > 0; off >>= 1)
        local += __shfl_down(local, off, 64);
    if (t == 0) slots[blockIdx.x] = (double)local;
}

__global__ __launch_bounds__(256) void ssim_finalize_kernel(
    const double* __restrict__ slots, float* __restrict__ out, double invN)
{
    __shared__ double red[4];
    const int t = threadIdx.x;
    double s = 0.0;
    for (int i = t; i < NBLK; i += 256) s += slots[i];
    #pragma unroll
    for (int off = 32; off > 0; off >>= 1)
        s += __shfl_down(s, off, 64);
    const int lane = t & 63, wid = t >> 6;
    if (lane == 0) red[wid] = s;
    __syncthreads();
    if (t == 0)
        out[0] = (float)(1.0 - (red[0] + red[1] + red[2] + red[3]) * invN);
}

extern "C" void kernel_launch(void* const* d_in, const int* in_sizes, int n_in,
                              void* d_out, int out_size, void* d_ws, size_t ws_size,
                              hipStream_t stream)
{
    const float* pred   = (const float*)d_in[0];
    const float* target = (const float*)d_in[1];
    const float* window = (const float*)d_in[2];
    float*  out   = (float*)d_out;
    double* slots = (double*)d_ws;     // NBLK*8 = 24 KB; every slot written
                                       // each launch (poison overwritten).

    ssim_wave_kernel<<<NBLK, 64, 0, stream>>>(pred, target, window, slots);

    const double invN = 1.0 / ((double)IMGN * IMGH * IMGW);
    ssim_finalize_kernel<<<1, 256, 0, stream>>>(slots, out, invN);
}